// Round 9
// baseline (149.230 us; speedup 1.0000x reference)
//
#include <hip/hip_runtime.h>

typedef unsigned short u16;
typedef unsigned int u32;
typedef unsigned long long u64;
typedef __bf16 bf16x8 __attribute__((ext_vector_type(8)));
typedef float f32x4 __attribute__((ext_vector_type(4)));

#define MFMA16(a, b, c) __builtin_amdgcn_mfma_f32_16x16x32_bf16(a, b, c, 0, 0, 0)

static __device__ __forceinline__ u16 f2bf(float f) {
  union { float f; u32 u; } v; v.f = f;
  u32 u = v.u;
  u32 r = (u + 0x7FFFu + ((u >> 16) & 1u)) >> 16;  // RNE
  return (u16)r;
}

static __device__ __forceinline__ bf16x8 ld16(const u16* p) {
  return __builtin_bit_cast(bf16x8, *(const uint4*)p);
}

static __device__ __forceinline__ u64 u64min(u64 a, u64 b) { return a < b ? a : b; }

// In-wave bitonic sort of 64 u64 keys, ascending by lane (single).
static __device__ __forceinline__ u64 bitonic64(u64 v, int lane) {
#pragma unroll
  for (int k = 2; k <= 64; k <<= 1) {
#pragma unroll
    for (int j = k >> 1; j > 0; j >>= 1) {
      u64 o = __shfl_xor(v, j, 64);
      bool up = ((lane & k) == 0);
      bool lower = ((lane & j) == 0);
      u64 mn = v < o ? v : o;
      u64 mx = v < o ? o : v;
      v = (lower == up) ? mn : mx;
    }
  }
  return v;
}

// Fused 2-wide bitonic sorts (independent values — interleaved for shuffle
// ILP; per-value op sequence identical to the single version → same results).
static __device__ __forceinline__ void bitonic64_2(u64& a, u64& b, int lane) {
#pragma unroll
  for (int k = 2; k <= 64; k <<= 1) {
#pragma unroll
    for (int j = k >> 1; j > 0; j >>= 1) {
      u64 oa = __shfl_xor(a, j, 64);
      u64 ob = __shfl_xor(b, j, 64);
      bool up = ((lane & k) == 0);
      bool lower = ((lane & j) == 0);
      bool sel = (lower == up);
      u64 mna = a < oa ? a : oa, mxa = a < oa ? oa : a;
      u64 mnb = b < ob ? b : ob, mxb = b < ob ? ob : b;
      a = sel ? mna : mxa;
      b = sel ? mnb : mxb;
    }
  }
}

// 32-element variant: the 64 network truncated to k<=32 (j<=16 → exchanges
// confined within lane halves; lanes 32-63 carry padding and never touch
// lanes 0-31). Sorted result in lanes 0..31. 15 stages vs 21.
static __device__ __forceinline__ void bitonic32_2(u64& a, u64& b, int lane) {
#pragma unroll
  for (int k = 2; k <= 32; k <<= 1) {
#pragma unroll
    for (int j = k >> 1; j > 0; j >>= 1) {
      u64 oa = __shfl_xor(a, j, 64);
      u64 ob = __shfl_xor(b, j, 64);
      bool up = ((lane & k) == 0);
      bool lower = ((lane & j) == 0);
      bool sel = (lower == up);
      u64 mna = a < oa ? a : oa, mxa = a < oa ? oa : a;
      u64 mnb = b < ob ? b : ob, mxb = b < ob ? ob : b;
      a = sel ? mna : mxa;
      b = sel ? mnb : mxb;
    }
  }
}

// monotone u32 key from f32 bits — pure integer transform (safe to duplicate)
static __device__ __forceinline__ u32 fkey(float f) {
  u32 bb = __float_as_uint(f);
  u32 sgn = (u32)((int)bb >> 31);
  return bb ^ (sgn | 0x80000000u);
}

// exact inverse of fkey (bijective; valid since no NaN in this kernel)
static __device__ __forceinline__ float ikey(u32 k) {
  u32 bb = (k & 0x80000000u) ? (k ^ 0x80000000u) : ~k;
  return __uint_as_float(bb);
}

// Reference fp32 distance semantics (matches np, verified r3..r16):
//   dot = fma(z,bz, fma(y,by, mul(x,bx)));  d2 = fl(fl(s1+s2) - fl(2*dot))
// PURE function of (x,y,z,s1,c) — safe to recompute per pass, bit-identical.
static __device__ __forceinline__ float d2of(float x, float y, float z, float s1,
                                             f32x4 c) {
  float dt = __builtin_fmaf(z, c[2], __builtin_fmaf(y, c[1], __fmul_rn(x, c[0])));
  return __fsub_rn(__fadd_rn(s1, c[3]), __fmul_rn(2.0f, dt));
}

// build candidate (x,y,z,s2) from global xyz2 — s2 rounding IDENTICAL to the
// old staged version: fl(fl(fl(x*x)+fl(y*y))+fl(z*z)) → bit-identical d2.
static __device__ __forceinline__ f32x4 candOf(const float* X2, int m) {
  float cx = X2[m], cy = X2[4096 + m], cz = X2[8192 + m];
  float cs = __fadd_rn(__fadd_rn(__fmul_rn(cx, cx), __fmul_rn(cy, cy)),
                       __fmul_rn(cz, cz));
  f32x4 c = {cx, cy, cz, cs};
  return c;
}

// ---------------------------------------------------------------------------
// K1: PREP + KNN-16.
// r9: NO candL — candidates read straight from global (xyz2 = 48 KB/batch,
// L2/L1-resident; raw re-read traffic ~786 MB << L2 BW, overlapped). This
// removes the 64 KB LDS block that capped residency at 2 blocks/CU (16
// waves/CU): r8 proved the 1024-thread exact-fit route fails (occupancy flat,
// dur +10 µs). New shape: 2048 blocks x 256 threads (4 waves), ONE row-pair
// per wave (8 rows/block). LDS/block = 8448 B (transpose tile ∪ surv 4 KB)
// → residency limited by threads/VGPR: __launch_bounds__(256,7) (2nd arg =
// min-BLOCKS-per-CU on this toolchain, r1/r2) → 28 waves/CU = 7 waves/SIMD,
// all budgets slack (1792 thr, 59 KB LDS). SPILL TRIPWIRE: VGPR==72 AND
// FETCH >> 10 MB → revert to r7. All verified machinery (pair sweeps, r7
// binary-search tau, ballot+mbcnt compaction, bitonic32/64_2, cold path)
// verbatim — only the candidate fetch source changed (bit-identical math).
// ---------------------------------------------------------------------------
__global__ __launch_bounds__(256, 7) void knn_prep(
    const float* __restrict__ xyz1, const float* __restrict__ xyz2,
    const float* __restrict__ points1, const float* __restrict__ points2,
    const float* __restrict__ W1, const float* __restrict__ W2,
    u16* __restrict__ p1t, u16* __restrict__ p2t,
    u16* __restrict__ W1b, u16* __restrict__ W2b,
    int* __restrict__ knn) {
  __shared__ __align__(16) char LB[8448];    // tile (8448 B) ∪ surv (4 KB)
  u16* tile = (u16*)LB;
  u64 (*surv)[2][64] = (u64(*)[2][64])LB;    // [4][2][64] = 4096 B
  const int t = threadIdx.x;                 // 0..255
  const int lane = t & 63;
  const int w = t >> 6;                      // 0..3
  const int g = blockIdx.x;

  // ---- part 0: W cast (blocks 0..143, 256 threads each = 36864 items) ----
  if (g < 144) {
    int i = g * 256 + t;
    if (i < 128 * 160) {
      int r = i / 160, c = i - r * 160;
      W1b[i] = (c < 131) ? f2bf(W1[r * 131 + c]) : (u16)0;
    } else {
      int u = i - 128 * 160;
      W2b[u] = f2bf(W2[u]);
    }
  }

  // ---- part 1: transpose tiles on blocks 0..511 (r0-verbatim inner code);
  //      barriers unconditional so blocks >=512 stay convergent ------------
  {
    const bool doT = (g < 512);
    const float* src = (g < 256) ? points1 : points2;
    u16* dst = (g < 256) ? p1t : p2t;
    const int gb = g & 255;
    const int tb = gb >> 6;
    const int n0 = (gb & 63) << 6;
    const float* sp = src + ((size_t)tb << 18);
    if (doT) {
#pragma unroll
      for (int i = 0; i < 16; i++) {
        int d = (i << 2) + (t >> 6);
        int n = t & 63;
        tile[n * 66 + d] = f2bf(sp[((size_t)d << 12) + n0 + n]);
      }
    }
    __syncthreads();
    if (doT) {
      u16* dp = dst + ((size_t)(tb * 4096 + n0) << 6);
#pragma unroll
      for (int i = 0; i < 8; i++) {
        int n = (i << 3) + (t >> 5);
        int dp2 = t & 31;
        *(u32*)(dp + n * 64 + (dp2 << 1)) =
            *(const u32*)(tile + n * 66 + (dp2 << 1));
      }
    }
  }
  __syncthreads();  // tile reads complete before surv reuses the region

  // ---- part 3: KNN — each wave owns ONE row-pair; candidates from L2 -----
  const int b = g >> 9;              // 2048 blocks: 512 per batch
  const int rbase = (g & 511) << 3;  // 8 rows per block
  const float* X1 = xyz1 + b * 12288;
  const float* X2 = xyz2 + b * 12288;
  {
    const int n0 = rbase + (w << 1);
    const int n1 = n0 + 1;
    const int row0 = b * 4096 + n0;
    const int row1 = row0 + 1;
    const float x0 = X1[n0], y0 = X1[4096 + n0], z0 = X1[8192 + n0];
    const float x1 = X1[n1], y1 = X1[4096 + n1], z1 = X1[8192 + n1];
    const float s10 = __fadd_rn(__fadd_rn(__fmul_rn(x0, x0), __fmul_rn(y0, y0)),
                                __fmul_rn(z0, z0));
    const float s11 = __fadd_rn(__fadd_rn(__fmul_rn(x1, x1), __fmul_rn(y1, y1)),
                                __fmul_rn(z1, z1));

    // pass A: per-lane mins for both rows off one candidate stream
    float fm0 = 3e38f, fm1 = 3e38f;
#pragma unroll 4
    for (int j = 0; j < 64; j++) {
      f32x4 c = candOf(X2, (j << 6) + lane);
      fm0 = fminf(fm0, d2of(x0, y0, z0, s10, c));
      fm1 = fminf(fm1, d2of(x1, y1, z1, s11, c));
    }

    // tau = 16th-smallest lane-min via 32-step binary search in fkey space
    // (monotone bijection; exact — r7 verified).
    const u32 k0 = fkey(fm0), k1 = fkey(fm1);
    u32 lo0 = 0u, hi0 = 0xFFFFFFFFu, lo1 = 0u, hi1 = 0xFFFFFFFFu;
#pragma unroll
    for (int it = 0; it < 32; it++) {
      u32 md0 = lo0 + ((hi0 - lo0) >> 1);
      u32 md1 = lo1 + ((hi1 - lo1) >> 1);
      bool ge0 = __popcll(__ballot(k0 <= md0)) >= 16;
      bool ge1 = __popcll(__ballot(k1 <= md1)) >= 16;
      hi0 = ge0 ? md0 : hi0;  lo0 = ge0 ? lo0 : md0 + 1;
      hi1 = ge1 ? md1 : hi1;  lo1 = ge1 ? lo1 : md1 + 1;
    }
    const float tau0 = ikey(hi0);
    const float tau1 = ikey(hi1);

    // pass B: filter both rows; per-row ballot+mbcnt compaction
    // (per-row j-order identical to r2..r8 verified code)
    u32 base0 = 0, base1 = 0;
#pragma unroll 4
    for (int j = 0; j < 64; j++) {
      const int m = (j << 6) + lane;
      f32x4 c = candOf(X2, m);
      float d0 = d2of(x0, y0, z0, s10, c);
      float d1 = d2of(x1, y1, z1, s11, c);
      bool p0 = d0 <= tau0;
      bool p1 = d1 <= tau1;
      u64 mk0 = __ballot(p0);
      u64 mk1 = __ballot(p1);
      if (mk0) {
        if (p0) {
          u32 pre = __builtin_amdgcn_mbcnt_lo((u32)mk0, 0u);
          pre = __builtin_amdgcn_mbcnt_hi((u32)(mk0 >> 32), pre);
          u32 slot = base0 + pre;
          if (slot < 64u) surv[w][0][slot] = ((u64)fkey(d0) << 32) | (u32)m;
        }
        base0 += (u32)__popcll(mk0);
      }
      if (mk1) {
        if (p1) {
          u32 pre = __builtin_amdgcn_mbcnt_lo((u32)mk1, 0u);
          pre = __builtin_amdgcn_mbcnt_hi((u32)(mk1 >> 32), pre);
          u32 slot = base1 + pre;
          if (slot < 64u) surv[w][1][slot] = ((u64)fkey(d1) << 32) | (u32)m;
        }
        base1 += (u32)__popcll(mk1);
      }
    }
    const u32 S0 = base0, S1 = base1;  // wave-uniform

    const u32 Smax = max(S0, S1);
    if (Smax <= 32) {
      // common case (E[S]≈16-20): 15-stage sort confined to lanes 0-31
      u64 v0 = (lane < (int)S0) ? surv[w][0][lane] : ~0ull;
      u64 v1 = (lane < (int)S1) ? surv[w][1][lane] : ~0ull;
      bitonic32_2(v0, v1, lane);
      if (lane < 16) {
        knn[row0 * 16 + lane] = (int)(v0 & 0xFFFFFFFFull);
        knn[row1 * 16 + lane] = (int)(v1 & 0xFFFFFFFFull);
      }
    } else if (Smax <= 64) {
      u64 v0 = (lane < (int)S0) ? surv[w][0][lane] : ~0ull;
      u64 v1 = (lane < (int)S1) ? surv[w][1][lane] : ~0ull;
      bitonic64_2(v0, v1, lane);
      if (lane < 16) {
        knn[row0 * 16 + lane] = (int)(v0 & 0xFFFFFFFFull);
        knn[row1 * 16 + lane] = (int)(v1 & 0xFFFFFFFFull);
      }
    } else {
      // rare: handle each row independently (hot single-sort or exact cold)
#pragma unroll 1
      for (int p = 0; p < 2; p++) {
        const u32 S = p ? S1 : S0;
        const int row = p ? row1 : row0;
        const float xx = p ? x1 : x0, yy = p ? y1 : y0, zz = p ? z1 : z0;
        const float ss = p ? s11 : s10;
        if (S <= 64) {
          u64 v = (lane < (int)S) ? surv[w][p][lane] : ~0ull;
          v = bitonic64(v, lane);
          if (lane < 16) knn[row * 16 + lane] = (int)(v & 0xFFFFFFFFull);
        } else {
          // exact cold path: increasing-order extraction, recompute from L2
          u64 prev = 0;
          for (int rr = 0; rr < 16; rr++) {
            u64 lm = ~0ull;
#pragma unroll 4
            for (int j = 0; j < 64; j++) {
              const int m = (j << 6) + lane;
              f32x4 c = candOf(X2, m);
              float d = d2of(xx, yy, zz, ss, c);
              u64 k64 = ((u64)fkey(d) << 32) | (u32)m;
              if (k64 > prev && k64 < lm) lm = k64;
            }
            u64 gm = lm;
#pragma unroll
            for (int off = 32; off; off >>= 1)
              gm = u64min(gm, __shfl_xor(gm, off, 64));
            if (lane == 0) knn[row * 16 + rr] = (int)(gm & 0xFFFFFFFFull);
            prev = gm;
          }
        }
      }
    }
  }
}

// ---------------------------------------------------------------------------
// K3: fused gather + MLP + weighted reduce (verbatim r9/r13/r15 — measured
// best; r16's 2x2 retile regressed via H1 write conflicts + W L1-thrash).
// Waves split the N-dim: each wave owns 32 output channels, covers all 128
// M-rows; W slice (18 KB) L1-resident; A-fragments shared from LDS.
// ---------------------------------------------------------------------------
__global__ __launch_bounds__(256, 3) void mlp_kernel(
    const float* __restrict__ xyz1, const float* __restrict__ xyz2,
    const u16* __restrict__ p1t, const u16* __restrict__ p2t,
    const int* __restrict__ knn,
    const u16* __restrict__ W1b, const float* __restrict__ b1,
    const u16* __restrict__ W2b, const float* __restrict__ b2,
    float* __restrict__ out) {
  __shared__ __align__(16) u16 F[128 * 168];
  __shared__ __align__(16) float winv[128];
  __shared__ __align__(16) float wnorm[128];
  __shared__ __align__(16) float outbuf[128 * 12];
  const int t = threadIdx.x;
  const int g = blockIdx.x;
  const int b = g >> 9;
  const int rbase = (g & 511) << 3;

  // ---- Phase A: build F = [p1 | p2[idx] | dir | 0-pad] --------------------
  {
    const int m = t >> 1, half = t & 1;
    const int n1 = rbase + (m >> 4);
    const uint4* s1p = (const uint4*)(p1t + ((size_t)(b * 4096 + n1) << 6)) + half * 4;
    uint4* d1p = (uint4*)(F + m * 168) + half * 4;
    d1p[0] = s1p[0]; d1p[1] = s1p[1]; d1p[2] = s1p[2]; d1p[3] = s1p[3];
    const int idx = knn[(((size_t)(b * 4096 + n1)) << 4) + (m & 15)];
    const uint4* s2p = (const uint4*)(p2t + ((size_t)(b * 4096 + idx) << 6)) + half * 4;
    uint4* d2p = (uint4*)(F + m * 168 + 64) + half * 4;
    d2p[0] = s2p[0]; d2p[1] = s2p[1]; d2p[2] = s2p[2]; d2p[3] = s2p[3];
  }
  if (t < 128) {
    const int m = t;
    const int n1 = rbase + (m >> 4);
    const int idx = knn[(((size_t)(b * 4096 + n1)) << 4) + (m & 15)];
    const float* X1 = xyz1 + b * 12288;
    const float* X2 = xyz2 + b * 12288;
    float dx = X2[idx] - X1[n1];
    float dy = X2[4096 + idx] - X1[4096 + n1];
    float dz = X2[8192 + idx] - X1[8192 + n1];
    u32 u0 = (u32)f2bf(dx) | ((u32)f2bf(dy) << 16);
    u32 u1 = (u32)f2bf(dz);
    uint4 pk = make_uint4(u0, u1, 0u, 0u);
    *(uint4*)(F + m * 168 + 128) = pk;
    float d = sqrtf(dx * dx + dy * dy + dz * dz);
    winv[m] = 1.0f / fmaxf(d, 1e-10f);
  } else {
    const int m = t - 128;
    uint4 zz = make_uint4(0u, 0u, 0u, 0u);
    uint4* zp = (uint4*)(F + m * 168 + 136);
    zp[0] = zz; zp[1] = zz; zp[2] = zz; zp[3] = zz;
  }
  __syncthreads();  // barrier 1: F + winv visible

  if (t < 128) {
    const int r = t >> 4;
    float s = 0.f;
#pragma unroll
    for (int k = 0; k < 16; k++) s += winv[(r << 4) + k];
    wnorm[t] = winv[t] / s;
  }

  const int lane = t & 63;
  const int wid = t >> 6;
  const int l15 = lane & 15;
  const int quad = lane >> 4;
  const int koff = quad << 3;
  const int nbase = wid << 5;

  // ---- GEMM1 -------------------------------------------------------------
  f32x4 acc[8][2];
  const f32x4 z4 = {0.f, 0.f, 0.f, 0.f};
#pragma unroll
  for (int i = 0; i < 8; i++)
#pragma unroll
    for (int j = 0; j < 2; j++) acc[i][j] = z4;

#pragma unroll
  for (int s = 0; s < 5; s++) {
    bf16x8 bf0 = ld16(W1b + (nbase + l15) * 160 + s * 32 + koff);
    bf16x8 bf1 = ld16(W1b + (nbase + 16 + l15) * 160 + s * 32 + koff);
#pragma unroll
    for (int mt = 0; mt < 8; mt++) {
      bf16x8 a = ld16(F + (mt * 16 + l15) * 168 + s * 32 + koff);
      acc[mt][0] = MFMA16(a, bf0, acc[mt][0]);
      acc[mt][1] = MFMA16(a, bf1, acc[mt][1]);
    }
  }
  __syncthreads();  // barrier 2: GEMM1 reads done before H1 overwrite

  {
    const float bv0 = b1[nbase + l15];
    const float bv1 = b1[nbase + 16 + l15];
#pragma unroll
    for (int mt = 0; mt < 8; mt++) {
      u16* hrow = F + (mt * 16 + quad * 4) * 168;
#pragma unroll
      for (int r = 0; r < 4; r++) {
        float zv0 = acc[mt][0][r] + bv0;
        zv0 = (zv0 >= 0.f) ? zv0 : 0.1f * zv0;
        hrow[r * 168 + nbase + l15] = f2bf(zv0);
        float zv1 = acc[mt][1][r] + bv1;
        zv1 = (zv1 >= 0.f) ? zv1 : 0.1f * zv1;
        hrow[r * 168 + nbase + 16 + l15] = f2bf(zv1);
      }
    }
  }
  __syncthreads();  // barrier 3: H1 visible

  // ---- GEMM2 -------------------------------------------------------------
  f32x4 acc2[8][2];
#pragma unroll
  for (int i = 0; i < 8; i++)
#pragma unroll
    for (int j = 0; j < 2; j++) acc2[i][j] = z4;

#pragma unroll
  for (int s = 0; s < 4; s++) {
    bf16x8 bf0 = ld16(W2b + (nbase + l15) * 128 + s * 32 + koff);
    bf16x8 bf1 = ld16(W2b + (nbase + 16 + l15) * 128 + s * 32 + koff);
#pragma unroll
    for (int mt = 0; mt < 8; mt++) {
      bf16x8 a = ld16(F + (mt * 16 + l15) * 168 + s * 32 + koff);
      acc2[mt][0] = MFMA16(a, bf0, acc2[mt][0]);
      acc2[mt][1] = MFMA16(a, bf1, acc2[mt][1]);
    }
  }

  {
    const float bv0 = b2[nbase + l15];
    const float bv1 = b2[nbase + 16 + l15];
#pragma unroll
    for (int mt = 0; mt < 8; mt++) {
      const f32x4 w4 = *(const f32x4*)&wnorm[(mt << 4) + (quad << 2)];
      float p0 = 0.f, p1 = 0.f;
#pragma unroll
      for (int r = 0; r < 4; r++) {
        float zv0 = acc2[mt][0][r] + bv0;
        zv0 = (zv0 >= 0.f) ? zv0 : 0.1f * zv0;
        p0 += zv0 * w4[r];
        float zv1 = acc2[mt][1][r] + bv1;
        zv1 = (zv1 >= 0.f) ? zv1 : 0.1f * zv1;
        p1 += zv1 * w4[r];
      }
      p0 += __shfl_xor(p0, 16); p0 += __shfl_xor(p0, 32);
      p1 += __shfl_xor(p1, 16); p1 += __shfl_xor(p1, 32);
      if (quad == 0) {
        outbuf[(nbase + l15) * 12 + mt] = p0;
        outbuf[(nbase + 16 + l15) * 12 + mt] = p1;
      }
    }
  }
  __syncthreads();  // barrier 4: outbuf visible
  {
    const int ch = t >> 1, half = t & 1;
    f32x4 v = *(const f32x4*)&outbuf[ch * 12 + (half << 2)];
    float* op = out + (((size_t)(b * 128 + ch)) << 12) + rbase + (half << 2);
    *(f32x4*)op = v;
  }
}

// ---------------------------------------------------------------------------
extern "C" void kernel_launch(void* const* d_in, const int* in_sizes, int n_in,
                              void* d_out, int out_size, void* d_ws, size_t ws_size,
                              hipStream_t stream) {
  const float* xyz1 = (const float*)d_in[0];
  const float* xyz2 = (const float*)d_in[1];
  const float* points1 = (const float*)d_in[2];
  const float* points2 = (const float*)d_in[3];
  const float* W1 = (const float*)d_in[4];
  const float* b1 = (const float*)d_in[5];
  const float* W2 = (const float*)d_in[6];
  const float* b2 = (const float*)d_in[7];
  float* out = (float*)d_out;

  char* ws = (char*)d_ws;
  int* knn = (int*)ws;                        // 1,048,576 B
  u16* p1t = (u16*)(ws + 1048576);            // 2,097,152 B
  u16* p2t = (u16*)(ws + 3145728);            // 2,097,152 B
  u16* W1b = (u16*)(ws + 5242880);            // 40,960 B
  u16* W2b = (u16*)(ws + 5283840);            // 32,768 B

  hipLaunchKernelGGL(knn_prep, dim3(2048), dim3(256), 0, stream,
                     xyz1, xyz2, points1, points2, W1, W2, p1t, p2t, W1b, W2b, knn);
  hipLaunchKernelGGL(mlp_kernel, dim3(2048), dim3(256), 0, stream,
                     xyz1, xyz2, p1t, p2t, knn, W1b, b1, W2b, b2, out);
}

// Round 10
// 141.329 us; speedup vs baseline: 1.0559x; 1.0559x over previous
//
#include <hip/hip_runtime.h>

typedef unsigned short u16;
typedef unsigned int u32;
typedef unsigned long long u64;
typedef __bf16 bf16x8 __attribute__((ext_vector_type(8)));
typedef float f32x4 __attribute__((ext_vector_type(4)));

#define MFMA16(a, b, c) __builtin_amdgcn_mfma_f32_16x16x32_bf16(a, b, c, 0, 0, 0)

static __device__ __forceinline__ u16 f2bf(float f) {
  union { float f; u32 u; } v; v.f = f;
  u32 u = v.u;
  u32 r = (u + 0x7FFFu + ((u >> 16) & 1u)) >> 16;  // RNE
  return (u16)r;
}

static __device__ __forceinline__ bf16x8 ld16(const u16* p) {
  return __builtin_bit_cast(bf16x8, *(const uint4*)p);
}

static __device__ __forceinline__ u64 u64min(u64 a, u64 b) { return a < b ? a : b; }

// In-wave bitonic sort of 64 u64 keys, ascending by lane (single).
static __device__ __forceinline__ u64 bitonic64(u64 v, int lane) {
#pragma unroll
  for (int k = 2; k <= 64; k <<= 1) {
#pragma unroll
    for (int j = k >> 1; j > 0; j >>= 1) {
      u64 o = __shfl_xor(v, j, 64);
      bool up = ((lane & k) == 0);
      bool lower = ((lane & j) == 0);
      u64 mn = v < o ? v : o;
      u64 mx = v < o ? o : v;
      v = (lower == up) ? mn : mx;
    }
  }
  return v;
}

// Fused 4-wide bitonic sorts (independent values — interleaved for shuffle
// ILP; per-value op sequence identical to the single version → same results).
static __device__ __forceinline__ void bitonic64_4(u64& a, u64& b, u64& c,
                                                   u64& d, int lane) {
#pragma unroll
  for (int k = 2; k <= 64; k <<= 1) {
#pragma unroll
    for (int j = k >> 1; j > 0; j >>= 1) {
      u64 oa = __shfl_xor(a, j, 64);
      u64 ob = __shfl_xor(b, j, 64);
      u64 oc = __shfl_xor(c, j, 64);
      u64 od = __shfl_xor(d, j, 64);
      bool up = ((lane & k) == 0);
      bool lower = ((lane & j) == 0);
      bool sel = (lower == up);
      u64 mna = a < oa ? a : oa, mxa = a < oa ? oa : a;
      u64 mnb = b < ob ? b : ob, mxb = b < ob ? ob : b;
      u64 mnc = c < oc ? c : oc, mxc = c < oc ? oc : c;
      u64 mnd = d < od ? d : od, mxd = d < od ? od : d;
      a = sel ? mna : mxa;
      b = sel ? mnb : mxb;
      c = sel ? mnc : mxc;
      d = sel ? mnd : mxd;
    }
  }
}

// 32-element variant: the 64 network truncated to k<=32 (j<=16 → all
// exchanges confined within lane halves; lanes 32-63 carry padding and
// never touch lanes 0-31). Sorted result in lanes 0..31. 15 stages vs 21.
static __device__ __forceinline__ void bitonic32_4(u64& a, u64& b, u64& c,
                                                   u64& d, int lane) {
#pragma unroll
  for (int k = 2; k <= 32; k <<= 1) {
#pragma unroll
    for (int j = k >> 1; j > 0; j >>= 1) {
      u64 oa = __shfl_xor(a, j, 64);
      u64 ob = __shfl_xor(b, j, 64);
      u64 oc = __shfl_xor(c, j, 64);
      u64 od = __shfl_xor(d, j, 64);
      bool up = ((lane & k) == 0);
      bool lower = ((lane & j) == 0);
      bool sel = (lower == up);
      u64 mna = a < oa ? a : oa, mxa = a < oa ? oa : a;
      u64 mnb = b < ob ? b : ob, mxb = b < ob ? ob : b;
      u64 mnc = c < oc ? c : oc, mxc = c < oc ? oc : c;
      u64 mnd = d < od ? d : od, mxd = d < od ? od : d;
      a = sel ? mna : mxa;
      b = sel ? mnb : mxb;
      c = sel ? mnc : mxc;
      d = sel ? mnd : mxd;
    }
  }
}

// monotone u32 key from f32 bits — pure integer transform (safe to duplicate)
static __device__ __forceinline__ u32 fkey(float f) {
  u32 bb = __float_as_uint(f);
  u32 sgn = (u32)((int)bb >> 31);
  return bb ^ (sgn | 0x80000000u);
}

// exact inverse of fkey (bijective; valid since no NaN in this kernel)
static __device__ __forceinline__ float ikey(u32 k) {
  u32 bb = (k & 0x80000000u) ? (k ^ 0x80000000u) : ~k;
  return __uint_as_float(bb);
}

// Reference fp32 distance semantics (matches np, verified r3..r16):
//   dot = fma(z,bz, fma(y,by, mul(x,bx)));  d2 = fl(fl(s1+s2) - fl(2*dot))
// PURE function of (x,y,z,s1,c) — safe to recompute per pass, bit-identical.
static __device__ __forceinline__ float d2of(float x, float y, float z, float s1,
                                             f32x4 c) {
  float dt = __builtin_fmaf(z, c[2], __builtin_fmaf(y, c[1], __fmul_rn(x, c[0])));
  return __fsub_rn(__fadd_rn(s1, c[3]), __fmul_rn(2.0f, dt));
}

// ---------------------------------------------------------------------------
// K1: PREP + KNN-16 — REVERT to the r7 shape (best verified: 42.6 µs).
// r8 (2048-thread exact fit) and r9 (candL dropped, candidates from L2) both
// regressed: the 64 KB block-shared candL at 2 blocks/CU / 16 waves/CU is
// the structural optimum — LDS latency 120cy + bank-parallel feed beats L2
// (~200cy) and the thread-capacity exact fit never co-schedules.
// Structure: 512-thread blocks (8 waves) share one 64 KB candL; quad-sharing
// (one candL sweep feeds all 4 wave rows, r6); tau via integer binary search
// in fkey space (r7); bitonic32 short survivor sort. keys[] eliminated via
// bit-identical recompute passes (r3). __launch_bounds__(512,2): 2nd arg =
// min-BLOCKS-per-CU on this toolchain (r1/r2 evidence).
// r10 delta vs r7: tau binary search truncated 32 → 24 steps. EXACT: the
// loop invariant count(lane-min keys <= hi) >= 16 holds at every step, so
// tau = ikey(hi) admits >= 16 candidates → survivors ⊇ true top-16; the
// sort-and-take-16 (any-S paths) then returns exactly the reference top-16
// with identical (d, index) tie-break. Interval after 24 steps <= 256 ulps
// → negligible survivor inflation. Saves 32 serial ballot steps per quad.
// ---------------------------------------------------------------------------
__global__ __launch_bounds__(512, 2) void knn_prep(
    const float* __restrict__ xyz1, const float* __restrict__ xyz2,
    const float* __restrict__ points1, const float* __restrict__ points2,
    const float* __restrict__ W1, const float* __restrict__ W2,
    u16* __restrict__ p1t, u16* __restrict__ p2t,
    u16* __restrict__ W1b, u16* __restrict__ W2b,
    int* __restrict__ knn) {
  __shared__ __align__(16) char LB[65536];
  f32x4* candL = (f32x4*)LB;     // 4096 * 16 B (knn phase)
  u16* tile = (u16*)LB;          // 64*66*2 = 8448 B (transpose phase)
  __shared__ u64 surv[8][4][64]; // 16 KB
  const int t = threadIdx.x;
  const int lane = t & 63;
  const int w = t >> 6;
  const int g = blockIdx.x;

  // ---- part 0: W cast (blocks 0..71, 512 threads each = 36864 items) -----
  if (g < 72) {
    int i = g * 512 + t;
    if (i < 128 * 160) {
      int r = i / 160, c = i - r * 160;
      W1b[i] = (c < 131) ? f2bf(W1[r * 131 + c]) : (u16)0;
    } else {
      int u = i - 128 * 160;
      W2b[u] = f2bf(W2[u]);
    }
  }

  // ---- part 1: one transpose tile per block (512 threads) ----------------
  {
    const float* src = (g < 256) ? points1 : points2;
    u16* dst = (g < 256) ? p1t : p2t;
    const int gb = g & 255;
    const int tb = gb >> 6;
    const int n0 = (gb & 63) << 6;
    const float* sp = src + ((size_t)tb << 18);
#pragma unroll
    for (int i = 0; i < 8; i++) {
      int d = (i << 3) + (t >> 6);
      int n = t & 63;
      tile[n * 66 + d] = f2bf(sp[((size_t)d << 12) + n0 + n]);
    }
    __syncthreads();
    u16* dp = dst + ((size_t)(tb * 4096 + n0) << 6);
#pragma unroll
    for (int i = 0; i < 4; i++) {
      int n = (i << 4) + (t >> 5);
      int dp2 = t & 31;
      *(u32*)(dp + n * 64 + (dp2 << 1)) = *(const u32*)(tile + n * 66 + (dp2 << 1));
    }
  }
  __syncthreads();  // tile reads complete before candL overwrites the region

  // ---- part 2: stage candidates; SINGLE site computing s2 (r5 lesson) ----
  const int b = g >> 7;              // 512 blocks: 128 per batch
  const int rbase = (g & 127) << 5;  // 32 rows per block
  const float* X1 = xyz1 + b * 12288;
  const float* X2 = xyz2 + b * 12288;
#pragma unroll
  for (int i = 0; i < 8; i++) {
    int m = i * 512 + t;
    float x = X2[m], y = X2[4096 + m], z = X2[8192 + m];
    float s2 = __fadd_rn(__fadd_rn(__fmul_rn(x, x), __fmul_rn(y, y)),
                         __fmul_rn(z, z));
    f32x4 pk = {x, y, z, s2};
    candL[m] = pk;
  }
  __syncthreads();

  // ---- part 3: KNN — one QUAD: all 4 wave rows share each candL sweep ----
  {
    const int nq = rbase + (w << 2);
    const int rowq = b * 4096 + nq;
    const float x0 = X1[nq + 0], y0 = X1[4096 + nq + 0], z0 = X1[8192 + nq + 0];
    const float x1 = X1[nq + 1], y1 = X1[4096 + nq + 1], z1 = X1[8192 + nq + 1];
    const float x2 = X1[nq + 2], y2 = X1[4096 + nq + 2], z2 = X1[8192 + nq + 2];
    const float x3 = X1[nq + 3], y3 = X1[4096 + nq + 3], z3 = X1[8192 + nq + 3];
    const float s0 = __fadd_rn(__fadd_rn(__fmul_rn(x0, x0), __fmul_rn(y0, y0)),
                               __fmul_rn(z0, z0));
    const float s1 = __fadd_rn(__fadd_rn(__fmul_rn(x1, x1), __fmul_rn(y1, y1)),
                               __fmul_rn(z1, z1));
    const float s2 = __fadd_rn(__fadd_rn(__fmul_rn(x2, x2), __fmul_rn(y2, y2)),
                               __fmul_rn(z2, z2));
    const float s3 = __fadd_rn(__fadd_rn(__fmul_rn(x3, x3), __fmul_rn(y3, y3)),
                               __fmul_rn(z3, z3));

    // pass A: per-lane mins for all 4 rows off ONE candL sweep
    float fm0 = 3e38f, fm1 = 3e38f, fm2 = 3e38f, fm3 = 3e38f;
#pragma unroll 8
    for (int j = 0; j < 64; j++) {
      f32x4 c = candL[(j << 6) + lane];
      fm0 = fminf(fm0, d2of(x0, y0, z0, s0, c));
      fm1 = fminf(fm1, d2of(x1, y1, z1, s1, c));
      fm2 = fminf(fm2, d2of(x2, y2, z2, s2, c));
      fm3 = fminf(fm3, d2of(x3, y3, z3, s3, c));
    }

    // tau: 24-step binary search in fkey space. Invariant at every step:
    // count(lane-min keys <= hi) >= 16 → >=16 candidates <= ikey(hi) →
    // survivors ⊇ top-16; sort+take-16 downstream is exact for any S.
    const u32 k0 = fkey(fm0), k1 = fkey(fm1), k2 = fkey(fm2), k3 = fkey(fm3);
    u32 lo0 = 0u, hi0 = 0xFFFFFFFFu, lo1 = 0u, hi1 = 0xFFFFFFFFu;
    u32 lo2 = 0u, hi2 = 0xFFFFFFFFu, lo3 = 0u, hi3 = 0xFFFFFFFFu;
#pragma unroll
    for (int it = 0; it < 24; it++) {
      u32 md0 = lo0 + ((hi0 - lo0) >> 1);
      u32 md1 = lo1 + ((hi1 - lo1) >> 1);
      u32 md2 = lo2 + ((hi2 - lo2) >> 1);
      u32 md3 = lo3 + ((hi3 - lo3) >> 1);
      bool ge0 = __popcll(__ballot(k0 <= md0)) >= 16;
      bool ge1 = __popcll(__ballot(k1 <= md1)) >= 16;
      bool ge2 = __popcll(__ballot(k2 <= md2)) >= 16;
      bool ge3 = __popcll(__ballot(k3 <= md3)) >= 16;
      hi0 = ge0 ? md0 : hi0;  lo0 = ge0 ? lo0 : md0 + 1;
      hi1 = ge1 ? md1 : hi1;  lo1 = ge1 ? lo1 : md1 + 1;
      hi2 = ge2 ? md2 : hi2;  lo2 = ge2 ? lo2 : md2 + 1;
      hi3 = ge3 ? md3 : hi3;  lo3 = ge3 ? lo3 : md3 + 1;
    }
    const float tau0 = ikey(hi0);
    const float tau1 = ikey(hi1);
    const float tau2 = ikey(hi2);
    const float tau3 = ikey(hi3);

    // pass B: filter all 4 rows off ONE sweep; per-row ballot+mbcnt
    // compaction (per-row j-order identical to r2..r7 verified code)
    u32 base0 = 0, base1 = 0, base2 = 0, base3 = 0;
#pragma unroll 4
    for (int j = 0; j < 64; j++) {
      const int m = (j << 6) + lane;
      f32x4 c = candL[m];
      float d0 = d2of(x0, y0, z0, s0, c);
      float d1 = d2of(x1, y1, z1, s1, c);
      float d2 = d2of(x2, y2, z2, s2, c);
      float d3 = d2of(x3, y3, z3, s3, c);
      bool p0 = d0 <= tau0;
      bool p1 = d1 <= tau1;
      bool p2 = d2 <= tau2;
      bool p3 = d3 <= tau3;
      u64 mk0 = __ballot(p0);
      u64 mk1 = __ballot(p1);
      u64 mk2 = __ballot(p2);
      u64 mk3 = __ballot(p3);
      if (mk0) {
        if (p0) {
          u32 pre = __builtin_amdgcn_mbcnt_lo((u32)mk0, 0u);
          pre = __builtin_amdgcn_mbcnt_hi((u32)(mk0 >> 32), pre);
          u32 slot = base0 + pre;
          if (slot < 64u) surv[w][0][slot] = ((u64)fkey(d0) << 32) | (u32)m;
        }
        base0 += (u32)__popcll(mk0);
      }
      if (mk1) {
        if (p1) {
          u32 pre = __builtin_amdgcn_mbcnt_lo((u32)mk1, 0u);
          pre = __builtin_amdgcn_mbcnt_hi((u32)(mk1 >> 32), pre);
          u32 slot = base1 + pre;
          if (slot < 64u) surv[w][1][slot] = ((u64)fkey(d1) << 32) | (u32)m;
        }
        base1 += (u32)__popcll(mk1);
      }
      if (mk2) {
        if (p2) {
          u32 pre = __builtin_amdgcn_mbcnt_lo((u32)mk2, 0u);
          pre = __builtin_amdgcn_mbcnt_hi((u32)(mk2 >> 32), pre);
          u32 slot = base2 + pre;
          if (slot < 64u) surv[w][2][slot] = ((u64)fkey(d2) << 32) | (u32)m;
        }
        base2 += (u32)__popcll(mk2);
      }
      if (mk3) {
        if (p3) {
          u32 pre = __builtin_amdgcn_mbcnt_lo((u32)mk3, 0u);
          pre = __builtin_amdgcn_mbcnt_hi((u32)(mk3 >> 32), pre);
          u32 slot = base3 + pre;
          if (slot < 64u) surv[w][3][slot] = ((u64)fkey(d3) << 32) | (u32)m;
        }
        base3 += (u32)__popcll(mk3);
      }
    }
    const u32 S0 = base0, S1 = base1, S2 = base2, S3 = base3;  // wave-uniform

    const u32 Smax = max(max(S0, S1), max(S2, S3));
    if (Smax <= 32) {
      // common case (E[S]≈16-20): 15-stage sort confined to lanes 0-31
      u64 v0 = (lane < (int)S0) ? surv[w][0][lane] : ~0ull;
      u64 v1 = (lane < (int)S1) ? surv[w][1][lane] : ~0ull;
      u64 v2 = (lane < (int)S2) ? surv[w][2][lane] : ~0ull;
      u64 v3 = (lane < (int)S3) ? surv[w][3][lane] : ~0ull;
      bitonic32_4(v0, v1, v2, v3, lane);
      if (lane < 16) {
        knn[(rowq + 0) * 16 + lane] = (int)(v0 & 0xFFFFFFFFull);
        knn[(rowq + 1) * 16 + lane] = (int)(v1 & 0xFFFFFFFFull);
        knn[(rowq + 2) * 16 + lane] = (int)(v2 & 0xFFFFFFFFull);
        knn[(rowq + 3) * 16 + lane] = (int)(v3 & 0xFFFFFFFFull);
      }
    } else if (Smax <= 64) {
      u64 v0 = (lane < (int)S0) ? surv[w][0][lane] : ~0ull;
      u64 v1 = (lane < (int)S1) ? surv[w][1][lane] : ~0ull;
      u64 v2 = (lane < (int)S2) ? surv[w][2][lane] : ~0ull;
      u64 v3 = (lane < (int)S3) ? surv[w][3][lane] : ~0ull;
      bitonic64_4(v0, v1, v2, v3, lane);
      if (lane < 16) {
        knn[(rowq + 0) * 16 + lane] = (int)(v0 & 0xFFFFFFFFull);
        knn[(rowq + 1) * 16 + lane] = (int)(v1 & 0xFFFFFFFFull);
        knn[(rowq + 2) * 16 + lane] = (int)(v2 & 0xFFFFFFFFull);
        knn[(rowq + 3) * 16 + lane] = (int)(v3 & 0xFFFFFFFFull);
      }
    } else {
      // rare: handle each row independently (hot single-sort or exact cold).
      // Row state selected via cndmask chains — NO runtime-indexed arrays.
#pragma unroll 1
      for (int p = 0; p < 4; p++) {
        const u32 S = (p & 2) ? ((p & 1) ? S3 : S2) : ((p & 1) ? S1 : S0);
        const int row = rowq + p;
        const float xx = (p & 2) ? ((p & 1) ? x3 : x2) : ((p & 1) ? x1 : x0);
        const float yy = (p & 2) ? ((p & 1) ? y3 : y2) : ((p & 1) ? y1 : y0);
        const float zz = (p & 2) ? ((p & 1) ? z3 : z2) : ((p & 1) ? z1 : z0);
        const float ss = (p & 2) ? ((p & 1) ? s3 : s2) : ((p & 1) ? s1 : s0);
        if (S <= 64) {
          u64 v = (lane < (int)S) ? surv[w][p][lane] : ~0ull;
          v = bitonic64(v, lane);
          if (lane < 16) knn[row * 16 + lane] = (int)(v & 0xFFFFFFFFull);
        } else {
          // exact cold path: increasing-order extraction, recompute from candL
          u64 prev = 0;
          for (int rr = 0; rr < 16; rr++) {
            u64 lm = ~0ull;
#pragma unroll 8
            for (int j = 0; j < 64; j++) {
              const int m = (j << 6) + lane;
              f32x4 c = candL[m];
              float d = d2of(xx, yy, zz, ss, c);
              u64 k64 = ((u64)fkey(d) << 32) | (u32)m;
              if (k64 > prev && k64 < lm) lm = k64;
            }
            u64 gm = lm;
#pragma unroll
            for (int off = 32; off; off >>= 1)
              gm = u64min(gm, __shfl_xor(gm, off, 64));
            if (lane == 0) knn[row * 16 + rr] = (int)(gm & 0xFFFFFFFFull);
            prev = gm;
          }
        }
      }
    }
  }
}

// ---------------------------------------------------------------------------
// K3: fused gather + MLP + weighted reduce (verbatim r9/r13/r15 — measured
// best; r16's 2x2 retile regressed via H1 write conflicts + W L1-thrash).
// Waves split the N-dim: each wave owns 32 output channels, covers all 128
// M-rows; W slice (18 KB) L1-resident; A-fragments shared from LDS.
// ---------------------------------------------------------------------------
__global__ __launch_bounds__(256, 3) void mlp_kernel(
    const float* __restrict__ xyz1, const float* __restrict__ xyz2,
    const u16* __restrict__ p1t, const u16* __restrict__ p2t,
    const int* __restrict__ knn,
    const u16* __restrict__ W1b, const float* __restrict__ b1,
    const u16* __restrict__ W2b, const float* __restrict__ b2,
    float* __restrict__ out) {
  __shared__ __align__(16) u16 F[128 * 168];
  __shared__ __align__(16) float winv[128];
  __shared__ __align__(16) float wnorm[128];
  __shared__ __align__(16) float outbuf[128 * 12];
  const int t = threadIdx.x;
  const int g = blockIdx.x;
  const int b = g >> 9;
  const int rbase = (g & 511) << 3;

  // ---- Phase A: build F = [p1 | p2[idx] | dir | 0-pad] --------------------
  {
    const int m = t >> 1, half = t & 1;
    const int n1 = rbase + (m >> 4);
    const uint4* s1p = (const uint4*)(p1t + ((size_t)(b * 4096 + n1) << 6)) + half * 4;
    uint4* d1p = (uint4*)(F + m * 168) + half * 4;
    d1p[0] = s1p[0]; d1p[1] = s1p[1]; d1p[2] = s1p[2]; d1p[3] = s1p[3];
    const int idx = knn[(((size_t)(b * 4096 + n1)) << 4) + (m & 15)];
    const uint4* s2p = (const uint4*)(p2t + ((size_t)(b * 4096 + idx) << 6)) + half * 4;
    uint4* d2p = (uint4*)(F + m * 168 + 64) + half * 4;
    d2p[0] = s2p[0]; d2p[1] = s2p[1]; d2p[2] = s2p[2]; d2p[3] = s2p[3];
  }
  if (t < 128) {
    const int m = t;
    const int n1 = rbase + (m >> 4);
    const int idx = knn[(((size_t)(b * 4096 + n1)) << 4) + (m & 15)];
    const float* X1 = xyz1 + b * 12288;
    const float* X2 = xyz2 + b * 12288;
    float dx = X2[idx] - X1[n1];
    float dy = X2[4096 + idx] - X1[4096 + n1];
    float dz = X2[8192 + idx] - X1[8192 + n1];
    u32 u0 = (u32)f2bf(dx) | ((u32)f2bf(dy) << 16);
    u32 u1 = (u32)f2bf(dz);
    uint4 pk = make_uint4(u0, u1, 0u, 0u);
    *(uint4*)(F + m * 168 + 128) = pk;
    float d = sqrtf(dx * dx + dy * dy + dz * dz);
    winv[m] = 1.0f / fmaxf(d, 1e-10f);
  } else {
    const int m = t - 128;
    uint4 zz = make_uint4(0u, 0u, 0u, 0u);
    uint4* zp = (uint4*)(F + m * 168 + 136);
    zp[0] = zz; zp[1] = zz; zp[2] = zz; zp[3] = zz;
  }
  __syncthreads();  // barrier 1: F + winv visible

  if (t < 128) {
    const int r = t >> 4;
    float s = 0.f;
#pragma unroll
    for (int k = 0; k < 16; k++) s += winv[(r << 4) + k];
    wnorm[t] = winv[t] / s;
  }

  const int lane = t & 63;
  const int wid = t >> 6;
  const int l15 = lane & 15;
  const int quad = lane >> 4;
  const int koff = quad << 3;
  const int nbase = wid << 5;

  // ---- GEMM1 -------------------------------------------------------------
  f32x4 acc[8][2];
  const f32x4 z4 = {0.f, 0.f, 0.f, 0.f};
#pragma unroll
  for (int i = 0; i < 8; i++)
#pragma unroll
    for (int j = 0; j < 2; j++) acc[i][j] = z4;

#pragma unroll
  for (int s = 0; s < 5; s++) {
    bf16x8 bf0 = ld16(W1b + (nbase + l15) * 160 + s * 32 + koff);
    bf16x8 bf1 = ld16(W1b + (nbase + 16 + l15) * 160 + s * 32 + koff);
#pragma unroll
    for (int mt = 0; mt < 8; mt++) {
      bf16x8 a = ld16(F + (mt * 16 + l15) * 168 + s * 32 + koff);
      acc[mt][0] = MFMA16(a, bf0, acc[mt][0]);
      acc[mt][1] = MFMA16(a, bf1, acc[mt][1]);
    }
  }
  __syncthreads();  // barrier 2: GEMM1 reads done before H1 overwrite

  {
    const float bv0 = b1[nbase + l15];
    const float bv1 = b1[nbase + 16 + l15];
#pragma unroll
    for (int mt = 0; mt < 8; mt++) {
      u16* hrow = F + (mt * 16 + quad * 4) * 168;
#pragma unroll
      for (int r = 0; r < 4; r++) {
        float zv0 = acc[mt][0][r] + bv0;
        zv0 = (zv0 >= 0.f) ? zv0 : 0.1f * zv0;
        hrow[r * 168 + nbase + l15] = f2bf(zv0);
        float zv1 = acc[mt][1][r] + bv1;
        zv1 = (zv1 >= 0.f) ? zv1 : 0.1f * zv1;
        hrow[r * 168 + nbase + 16 + l15] = f2bf(zv1);
      }
    }
  }
  __syncthreads();  // barrier 3: H1 visible

  // ---- GEMM2 -------------------------------------------------------------
  f32x4 acc2[8][2];
#pragma unroll
  for (int i = 0; i < 8; i++)
#pragma unroll
    for (int j = 0; j < 2; j++) acc2[i][j] = z4;

#pragma unroll
  for (int s = 0; s < 4; s++) {
    bf16x8 bf0 = ld16(W2b + (nbase + l15) * 128 + s * 32 + koff);
    bf16x8 bf1 = ld16(W2b + (nbase + 16 + l15) * 128 + s * 32 + koff);
#pragma unroll
    for (int mt = 0; mt < 8; mt++) {
      bf16x8 a = ld16(F + (mt * 16 + l15) * 168 + s * 32 + koff);
      acc2[mt][0] = MFMA16(a, bf0, acc2[mt][0]);
      acc2[mt][1] = MFMA16(a, bf1, acc2[mt][1]);
    }
  }

  {
    const float bv0 = b2[nbase + l15];
    const float bv1 = b2[nbase + 16 + l15];
#pragma unroll
    for (int mt = 0; mt < 8; mt++) {
      const f32x4 w4 = *(const f32x4*)&wnorm[(mt << 4) + (quad << 2)];
      float p0 = 0.f, p1 = 0.f;
#pragma unroll
      for (int r = 0; r < 4; r++) {
        float zv0 = acc2[mt][0][r] + bv0;
        zv0 = (zv0 >= 0.f) ? zv0 : 0.1f * zv0;
        p0 += zv0 * w4[r];
        float zv1 = acc2[mt][1][r] + bv1;
        zv1 = (zv1 >= 0.f) ? zv1 : 0.1f * zv1;
        p1 += zv1 * w4[r];
      }
      p0 += __shfl_xor(p0, 16); p0 += __shfl_xor(p0, 32);
      p1 += __shfl_xor(p1, 16); p1 += __shfl_xor(p1, 32);
      if (quad == 0) {
        outbuf[(nbase + l15) * 12 + mt] = p0;
        outbuf[(nbase + 16 + l15) * 12 + mt] = p1;
      }
    }
  }
  __syncthreads();  // barrier 4: outbuf visible
  {
    const int ch = t >> 1, half = t & 1;
    f32x4 v = *(const f32x4*)&outbuf[ch * 12 + (half << 2)];
    float* op = out + (((size_t)(b * 128 + ch)) << 12) + rbase + (half << 2);
    *(f32x4*)op = v;
  }
}

// ---------------------------------------------------------------------------
extern "C" void kernel_launch(void* const* d_in, const int* in_sizes, int n_in,
                              void* d_out, int out_size, void* d_ws, size_t ws_size,
                              hipStream_t stream) {
  const float* xyz1 = (const float*)d_in[0];
  const float* xyz2 = (const float*)d_in[1];
  const float* points1 = (const float*)d_in[2];
  const float* points2 = (const float*)d_in[3];
  const float* W1 = (const float*)d_in[4];
  const float* b1 = (const float*)d_in[5];
  const float* W2 = (const float*)d_in[6];
  const float* b2 = (const float*)d_in[7];
  float* out = (float*)d_out;

  char* ws = (char*)d_ws;
  int* knn = (int*)ws;                        // 1,048,576 B
  u16* p1t = (u16*)(ws + 1048576);            // 2,097,152 B
  u16* p2t = (u16*)(ws + 3145728);            // 2,097,152 B
  u16* W1b = (u16*)(ws + 5242880);            // 40,960 B
  u16* W2b = (u16*)(ws + 5283840);            // 32,768 B

  hipLaunchKernelGGL(knn_prep, dim3(512), dim3(512), 0, stream,
                     xyz1, xyz2, points1, points2, W1, W2, p1t, p2t, W1b, W2b, knn);
  hipLaunchKernelGGL(mlp_kernel, dim3(2048), dim3(256), 0, stream,
                     xyz1, xyz2, p1t, p2t, knn, W1b, b1, W2b, b2, out);
}

// Round 11
// 140.804 us; speedup vs baseline: 1.0598x; 1.0037x over previous
//
#include <hip/hip_runtime.h>

typedef unsigned short u16;
typedef unsigned int u32;
typedef unsigned long long u64;
typedef __bf16 bf16x8 __attribute__((ext_vector_type(8)));
typedef float f32x4 __attribute__((ext_vector_type(4)));
typedef float f32x2 __attribute__((ext_vector_type(2)));

#define MFMA16(a, b, c) __builtin_amdgcn_mfma_f32_16x16x32_bf16(a, b, c, 0, 0, 0)

static __device__ __forceinline__ u16 f2bf(float f) {
  union { float f; u32 u; } v; v.f = f;
  u32 u = v.u;
  u32 r = (u + 0x7FFFu + ((u >> 16) & 1u)) >> 16;  // RNE
  return (u16)r;
}

static __device__ __forceinline__ bf16x8 ld16(const u16* p) {
  return __builtin_bit_cast(bf16x8, *(const uint4*)p);
}

static __device__ __forceinline__ u64 u64min(u64 a, u64 b) { return a < b ? a : b; }

// In-wave bitonic sort of 64 u64 keys, ascending by lane (single).
static __device__ __forceinline__ u64 bitonic64(u64 v, int lane) {
#pragma unroll
  for (int k = 2; k <= 64; k <<= 1) {
#pragma unroll
    for (int j = k >> 1; j > 0; j >>= 1) {
      u64 o = __shfl_xor(v, j, 64);
      bool up = ((lane & k) == 0);
      bool lower = ((lane & j) == 0);
      u64 mn = v < o ? v : o;
      u64 mx = v < o ? o : v;
      v = (lower == up) ? mn : mx;
    }
  }
  return v;
}

// Fused 4-wide bitonic sorts (independent values — interleaved for shuffle
// ILP; per-value op sequence identical to the single version → same results).
static __device__ __forceinline__ void bitonic64_4(u64& a, u64& b, u64& c,
                                                   u64& d, int lane) {
#pragma unroll
  for (int k = 2; k <= 64; k <<= 1) {
#pragma unroll
    for (int j = k >> 1; j > 0; j >>= 1) {
      u64 oa = __shfl_xor(a, j, 64);
      u64 ob = __shfl_xor(b, j, 64);
      u64 oc = __shfl_xor(c, j, 64);
      u64 od = __shfl_xor(d, j, 64);
      bool up = ((lane & k) == 0);
      bool lower = ((lane & j) == 0);
      bool sel = (lower == up);
      u64 mna = a < oa ? a : oa, mxa = a < oa ? oa : a;
      u64 mnb = b < ob ? b : ob, mxb = b < ob ? ob : b;
      u64 mnc = c < oc ? c : oc, mxc = c < oc ? oc : c;
      u64 mnd = d < od ? d : od, mxd = d < od ? od : d;
      a = sel ? mna : mxa;
      b = sel ? mnb : mxb;
      c = sel ? mnc : mxc;
      d = sel ? mnd : mxd;
    }
  }
}

// 32-element variant: the 64 network truncated to k<=32 (j<=16 → all
// exchanges confined within lane halves; lanes 32-63 carry padding and
// never touch lanes 0-31). Sorted result in lanes 0..31. 15 stages vs 21.
static __device__ __forceinline__ void bitonic32_4(u64& a, u64& b, u64& c,
                                                   u64& d, int lane) {
#pragma unroll
  for (int k = 2; k <= 32; k <<= 1) {
#pragma unroll
    for (int j = k >> 1; j > 0; j >>= 1) {
      u64 oa = __shfl_xor(a, j, 64);
      u64 ob = __shfl_xor(b, j, 64);
      u64 oc = __shfl_xor(c, j, 64);
      u64 od = __shfl_xor(d, j, 64);
      bool up = ((lane & k) == 0);
      bool lower = ((lane & j) == 0);
      bool sel = (lower == up);
      u64 mna = a < oa ? a : oa, mxa = a < oa ? oa : a;
      u64 mnb = b < ob ? b : ob, mxb = b < ob ? ob : b;
      u64 mnc = c < oc ? c : oc, mxc = c < oc ? oc : c;
      u64 mnd = d < od ? d : od, mxd = d < od ? od : d;
      a = sel ? mna : mxa;
      b = sel ? mnb : mxb;
      c = sel ? mnc : mxc;
      d = sel ? mnd : mxd;
    }
  }
}

// monotone u32 key from f32 bits — pure integer transform (safe to duplicate)
static __device__ __forceinline__ u32 fkey(float f) {
  u32 bb = __float_as_uint(f);
  u32 sgn = (u32)((int)bb >> 31);
  return bb ^ (sgn | 0x80000000u);
}

// exact inverse of fkey (bijective; valid since no NaN in this kernel)
static __device__ __forceinline__ float ikey(u32 k) {
  u32 bb = (k & 0x80000000u) ? (k ^ 0x80000000u) : ~k;
  return __uint_as_float(bb);
}

// Reference fp32 distance semantics (matches np, verified r3..r16):
//   dot = fma(z,bz, fma(y,by, mul(x,bx)));  d2 = fl(fl(s1+s2) - fl(2*dot))
// Scalar form (cold path). NOTE: fl(add - mul(2,dt)) ≡ fma(dt,-2,add)
// bitwise, since 2*dt is exact (exponent bump) and both round the same
// exact quantity once — the packed path below uses the fma form.
static __device__ __forceinline__ float d2of(float x, float y, float z, float s1,
                                             f32x4 c) {
  float dt = __builtin_fmaf(z, c[2], __builtin_fmaf(y, c[1], __fmul_rn(x, c[0])));
  return __fsub_rn(__fadd_rn(s1, c[3]), __fmul_rn(2.0f, dt));
}

// Packed 2-row distance: per-component ops are the same IEEE-RN operations
// as the scalar path (v_pk_mul/add/fma lanes ≡ __fmul_rn/__fadd_rn/fmaf),
// so results are bit-identical to d2of for each row.
static __device__ __forceinline__ f32x2 d2of2(f32x2 X, f32x2 Y, f32x2 Z,
                                              f32x2 S, f32x4 c) {
  f32x2 cx = {c[0], c[0]}, cy = {c[1], c[1]}, cz = {c[2], c[2]},
        cs = {c[3], c[3]};
  f32x2 m = X * cx;                                    // pk_mul
  f32x2 t = __builtin_elementwise_fma(Y, cy, m);       // pk_fma
  f32x2 dt = __builtin_elementwise_fma(Z, cz, t);      // pk_fma
  f32x2 sa = S + cs;                                   // pk_add
  const f32x2 n2 = {-2.0f, -2.0f};
  return __builtin_elementwise_fma(dt, n2, sa);        // pk_fma (exact ≡ sub)
}

// ---------------------------------------------------------------------------
// K1: PREP + KNN-16 — r7/r10 shape (best verified; r8 thread-exact-fit and
// r9 L2-direct both regressed — 64 KB candL @ 2 blocks/CU is the optimum).
// Structure: 512-thread blocks (8 waves) share one 64 KB candL; quad-sharing
// (one candL sweep feeds all 4 wave rows); tau via 24-step integer binary
// search in fkey space (truncation EXACT: invariant count(keys<=hi)>=16 →
// survivors ⊇ top-16, downstream sort+take-16 exact for any S — r10 pass).
// __launch_bounds__(512,2): 2nd arg = min-BLOCKS-per-CU here (r1/r2).
// r11 delta: d2of sweeps PACKED-FP32 (f32x2 rows {0,1},{2,3} → v_pk_mul/
// pk_add/pk_fma, LLVM selects VOP3P for <2 x float> on gfx90a+). Halves the
// sweep VALU (~28 → ~14-18 ops/candidate). Bit-exact: pk lanes are the same
// RN ops; the fma(dt,-2,sadd) form ≡ sub(sadd, 2*dt) bitwise (2*dt exact).
// ---------------------------------------------------------------------------
__global__ __launch_bounds__(512, 2) void knn_prep(
    const float* __restrict__ xyz1, const float* __restrict__ xyz2,
    const float* __restrict__ points1, const float* __restrict__ points2,
    const float* __restrict__ W1, const float* __restrict__ W2,
    u16* __restrict__ p1t, u16* __restrict__ p2t,
    u16* __restrict__ W1b, u16* __restrict__ W2b,
    int* __restrict__ knn) {
  __shared__ __align__(16) char LB[65536];
  f32x4* candL = (f32x4*)LB;     // 4096 * 16 B (knn phase)
  u16* tile = (u16*)LB;          // 64*66*2 = 8448 B (transpose phase)
  __shared__ u64 surv[8][4][64]; // 16 KB
  const int t = threadIdx.x;
  const int lane = t & 63;
  const int w = t >> 6;
  const int g = blockIdx.x;

  // ---- part 0: W cast (blocks 0..71, 512 threads each = 36864 items) -----
  if (g < 72) {
    int i = g * 512 + t;
    if (i < 128 * 160) {
      int r = i / 160, c = i - r * 160;
      W1b[i] = (c < 131) ? f2bf(W1[r * 131 + c]) : (u16)0;
    } else {
      int u = i - 128 * 160;
      W2b[u] = f2bf(W2[u]);
    }
  }

  // ---- part 1: one transpose tile per block (512 threads) ----------------
  {
    const float* src = (g < 256) ? points1 : points2;
    u16* dst = (g < 256) ? p1t : p2t;
    const int gb = g & 255;
    const int tb = gb >> 6;
    const int n0 = (gb & 63) << 6;
    const float* sp = src + ((size_t)tb << 18);
#pragma unroll
    for (int i = 0; i < 8; i++) {
      int d = (i << 3) + (t >> 6);
      int n = t & 63;
      tile[n * 66 + d] = f2bf(sp[((size_t)d << 12) + n0 + n]);
    }
    __syncthreads();
    u16* dp = dst + ((size_t)(tb * 4096 + n0) << 6);
#pragma unroll
    for (int i = 0; i < 4; i++) {
      int n = (i << 4) + (t >> 5);
      int dp2 = t & 31;
      *(u32*)(dp + n * 64 + (dp2 << 1)) = *(const u32*)(tile + n * 66 + (dp2 << 1));
    }
  }
  __syncthreads();  // tile reads complete before candL overwrites the region

  // ---- part 2: stage candidates; SINGLE site computing s2 (r5 lesson) ----
  const int b = g >> 7;              // 512 blocks: 128 per batch
  const int rbase = (g & 127) << 5;  // 32 rows per block
  const float* X1 = xyz1 + b * 12288;
  const float* X2 = xyz2 + b * 12288;
#pragma unroll
  for (int i = 0; i < 8; i++) {
    int m = i * 512 + t;
    float x = X2[m], y = X2[4096 + m], z = X2[8192 + m];
    float s2 = __fadd_rn(__fadd_rn(__fmul_rn(x, x), __fmul_rn(y, y)),
                         __fmul_rn(z, z));
    f32x4 pk = {x, y, z, s2};
    candL[m] = pk;
  }
  __syncthreads();

  // ---- part 3: KNN — one QUAD: all 4 wave rows share each candL sweep ----
  {
    const int nq = rbase + (w << 2);
    const int rowq = b * 4096 + nq;
    const float x0 = X1[nq + 0], y0 = X1[4096 + nq + 0], z0 = X1[8192 + nq + 0];
    const float x1 = X1[nq + 1], y1 = X1[4096 + nq + 1], z1 = X1[8192 + nq + 1];
    const float x2 = X1[nq + 2], y2 = X1[4096 + nq + 2], z2 = X1[8192 + nq + 2];
    const float x3 = X1[nq + 3], y3 = X1[4096 + nq + 3], z3 = X1[8192 + nq + 3];
    const float s0 = __fadd_rn(__fadd_rn(__fmul_rn(x0, x0), __fmul_rn(y0, y0)),
                               __fmul_rn(z0, z0));
    const float s1 = __fadd_rn(__fadd_rn(__fmul_rn(x1, x1), __fmul_rn(y1, y1)),
                               __fmul_rn(z1, z1));
    const float s2 = __fadd_rn(__fadd_rn(__fmul_rn(x2, x2), __fmul_rn(y2, y2)),
                               __fmul_rn(z2, z2));
    const float s3 = __fadd_rn(__fadd_rn(__fmul_rn(x3, x3), __fmul_rn(y3, y3)),
                               __fmul_rn(z3, z3));
    const f32x2 X01 = {x0, x1}, Y01 = {y0, y1}, Z01 = {z0, z1}, S01 = {s0, s1};
    const f32x2 X23 = {x2, x3}, Y23 = {y2, y3}, Z23 = {z2, z3}, S23 = {s2, s3};

    // pass A: per-lane mins for all 4 rows off ONE candL sweep (packed math)
    float fm0 = 3e38f, fm1 = 3e38f, fm2 = 3e38f, fm3 = 3e38f;
#pragma unroll 8
    for (int j = 0; j < 64; j++) {
      f32x4 c = candL[(j << 6) + lane];
      f32x2 d01 = d2of2(X01, Y01, Z01, S01, c);
      f32x2 d23 = d2of2(X23, Y23, Z23, S23, c);
      fm0 = fminf(fm0, d01[0]);
      fm1 = fminf(fm1, d01[1]);
      fm2 = fminf(fm2, d23[0]);
      fm3 = fminf(fm3, d23[1]);
    }

    // tau: 24-step binary search in fkey space. Invariant at every step:
    // count(lane-min keys <= hi) >= 16 → >=16 candidates <= ikey(hi) →
    // survivors ⊇ top-16; sort+take-16 downstream is exact for any S.
    const u32 k0 = fkey(fm0), k1 = fkey(fm1), k2 = fkey(fm2), k3 = fkey(fm3);
    u32 lo0 = 0u, hi0 = 0xFFFFFFFFu, lo1 = 0u, hi1 = 0xFFFFFFFFu;
    u32 lo2 = 0u, hi2 = 0xFFFFFFFFu, lo3 = 0u, hi3 = 0xFFFFFFFFu;
#pragma unroll
    for (int it = 0; it < 24; it++) {
      u32 md0 = lo0 + ((hi0 - lo0) >> 1);
      u32 md1 = lo1 + ((hi1 - lo1) >> 1);
      u32 md2 = lo2 + ((hi2 - lo2) >> 1);
      u32 md3 = lo3 + ((hi3 - lo3) >> 1);
      bool ge0 = __popcll(__ballot(k0 <= md0)) >= 16;
      bool ge1 = __popcll(__ballot(k1 <= md1)) >= 16;
      bool ge2 = __popcll(__ballot(k2 <= md2)) >= 16;
      bool ge3 = __popcll(__ballot(k3 <= md3)) >= 16;
      hi0 = ge0 ? md0 : hi0;  lo0 = ge0 ? lo0 : md0 + 1;
      hi1 = ge1 ? md1 : hi1;  lo1 = ge1 ? lo1 : md1 + 1;
      hi2 = ge2 ? md2 : hi2;  lo2 = ge2 ? lo2 : md2 + 1;
      hi3 = ge3 ? md3 : hi3;  lo3 = ge3 ? lo3 : md3 + 1;
    }
    const float tau0 = ikey(hi0);
    const float tau1 = ikey(hi1);
    const float tau2 = ikey(hi2);
    const float tau3 = ikey(hi3);

    // pass B: filter all 4 rows off ONE sweep (packed math); per-row
    // ballot+mbcnt compaction (per-row j-order identical to r2..r10)
    u32 base0 = 0, base1 = 0, base2 = 0, base3 = 0;
#pragma unroll 4
    for (int j = 0; j < 64; j++) {
      const int m = (j << 6) + lane;
      f32x4 c = candL[m];
      f32x2 d01 = d2of2(X01, Y01, Z01, S01, c);
      f32x2 d23 = d2of2(X23, Y23, Z23, S23, c);
      float d0 = d01[0], d1 = d01[1], d2 = d23[0], d3 = d23[1];
      bool p0 = d0 <= tau0;
      bool p1 = d1 <= tau1;
      bool p2 = d2 <= tau2;
      bool p3 = d3 <= tau3;
      u64 mk0 = __ballot(p0);
      u64 mk1 = __ballot(p1);
      u64 mk2 = __ballot(p2);
      u64 mk3 = __ballot(p3);
      if (mk0) {
        if (p0) {
          u32 pre = __builtin_amdgcn_mbcnt_lo((u32)mk0, 0u);
          pre = __builtin_amdgcn_mbcnt_hi((u32)(mk0 >> 32), pre);
          u32 slot = base0 + pre;
          if (slot < 64u) surv[w][0][slot] = ((u64)fkey(d0) << 32) | (u32)m;
        }
        base0 += (u32)__popcll(mk0);
      }
      if (mk1) {
        if (p1) {
          u32 pre = __builtin_amdgcn_mbcnt_lo((u32)mk1, 0u);
          pre = __builtin_amdgcn_mbcnt_hi((u32)(mk1 >> 32), pre);
          u32 slot = base1 + pre;
          if (slot < 64u) surv[w][1][slot] = ((u64)fkey(d1) << 32) | (u32)m;
        }
        base1 += (u32)__popcll(mk1);
      }
      if (mk2) {
        if (p2) {
          u32 pre = __builtin_amdgcn_mbcnt_lo((u32)mk2, 0u);
          pre = __builtin_amdgcn_mbcnt_hi((u32)(mk2 >> 32), pre);
          u32 slot = base2 + pre;
          if (slot < 64u) surv[w][2][slot] = ((u64)fkey(d2) << 32) | (u32)m;
        }
        base2 += (u32)__popcll(mk2);
      }
      if (mk3) {
        if (p3) {
          u32 pre = __builtin_amdgcn_mbcnt_lo((u32)mk3, 0u);
          pre = __builtin_amdgcn_mbcnt_hi((u32)(mk3 >> 32), pre);
          u32 slot = base3 + pre;
          if (slot < 64u) surv[w][3][slot] = ((u64)fkey(d3) << 32) | (u32)m;
        }
        base3 += (u32)__popcll(mk3);
      }
    }
    const u32 S0 = base0, S1 = base1, S2 = base2, S3 = base3;  // wave-uniform

    const u32 Smax = max(max(S0, S1), max(S2, S3));
    if (Smax <= 32) {
      // common case (E[S]≈16-20): 15-stage sort confined to lanes 0-31
      u64 v0 = (lane < (int)S0) ? surv[w][0][lane] : ~0ull;
      u64 v1 = (lane < (int)S1) ? surv[w][1][lane] : ~0ull;
      u64 v2 = (lane < (int)S2) ? surv[w][2][lane] : ~0ull;
      u64 v3 = (lane < (int)S3) ? surv[w][3][lane] : ~0ull;
      bitonic32_4(v0, v1, v2, v3, lane);
      if (lane < 16) {
        knn[(rowq + 0) * 16 + lane] = (int)(v0 & 0xFFFFFFFFull);
        knn[(rowq + 1) * 16 + lane] = (int)(v1 & 0xFFFFFFFFull);
        knn[(rowq + 2) * 16 + lane] = (int)(v2 & 0xFFFFFFFFull);
        knn[(rowq + 3) * 16 + lane] = (int)(v3 & 0xFFFFFFFFull);
      }
    } else if (Smax <= 64) {
      u64 v0 = (lane < (int)S0) ? surv[w][0][lane] : ~0ull;
      u64 v1 = (lane < (int)S1) ? surv[w][1][lane] : ~0ull;
      u64 v2 = (lane < (int)S2) ? surv[w][2][lane] : ~0ull;
      u64 v3 = (lane < (int)S3) ? surv[w][3][lane] : ~0ull;
      bitonic64_4(v0, v1, v2, v3, lane);
      if (lane < 16) {
        knn[(rowq + 0) * 16 + lane] = (int)(v0 & 0xFFFFFFFFull);
        knn[(rowq + 1) * 16 + lane] = (int)(v1 & 0xFFFFFFFFull);
        knn[(rowq + 2) * 16 + lane] = (int)(v2 & 0xFFFFFFFFull);
        knn[(rowq + 3) * 16 + lane] = (int)(v3 & 0xFFFFFFFFull);
      }
    } else {
      // rare: handle each row independently (hot single-sort or exact cold).
      // Row state selected via cndmask chains — NO runtime-indexed arrays.
#pragma unroll 1
      for (int p = 0; p < 4; p++) {
        const u32 S = (p & 2) ? ((p & 1) ? S3 : S2) : ((p & 1) ? S1 : S0);
        const int row = rowq + p;
        const float xx = (p & 2) ? ((p & 1) ? x3 : x2) : ((p & 1) ? x1 : x0);
        const float yy = (p & 2) ? ((p & 1) ? y3 : y2) : ((p & 1) ? y1 : y0);
        const float zz = (p & 2) ? ((p & 1) ? z3 : z2) : ((p & 1) ? z1 : z0);
        const float ss = (p & 2) ? ((p & 1) ? s3 : s2) : ((p & 1) ? s1 : s0);
        if (S <= 64) {
          u64 v = (lane < (int)S) ? surv[w][p][lane] : ~0ull;
          v = bitonic64(v, lane);
          if (lane < 16) knn[row * 16 + lane] = (int)(v & 0xFFFFFFFFull);
        } else {
          // exact cold path: increasing-order extraction, recompute from candL
          u64 prev = 0;
          for (int rr = 0; rr < 16; rr++) {
            u64 lm = ~0ull;
#pragma unroll 8
            for (int j = 0; j < 64; j++) {
              const int m = (j << 6) + lane;
              f32x4 c = candL[m];
              float d = d2of(xx, yy, zz, ss, c);
              u64 k64 = ((u64)fkey(d) << 32) | (u32)m;
              if (k64 > prev && k64 < lm) lm = k64;
            }
            u64 gm = lm;
#pragma unroll
            for (int off = 32; off; off >>= 1)
              gm = u64min(gm, __shfl_xor(gm, off, 64));
            if (lane == 0) knn[row * 16 + rr] = (int)(gm & 0xFFFFFFFFull);
            prev = gm;
          }
        }
      }
    }
  }
}

// ---------------------------------------------------------------------------
// K3: fused gather + MLP + weighted reduce (verbatim r9/r13/r15 — measured
// best; r16's 2x2 retile regressed via H1 write conflicts + W L1-thrash).
// Waves split the N-dim: each wave owns 32 output channels, covers all 128
// M-rows; W slice (18 KB) L1-resident; A-fragments shared from LDS.
// ---------------------------------------------------------------------------
__global__ __launch_bounds__(256, 3) void mlp_kernel(
    const float* __restrict__ xyz1, const float* __restrict__ xyz2,
    const u16* __restrict__ p1t, const u16* __restrict__ p2t,
    const int* __restrict__ knn,
    const u16* __restrict__ W1b, const float* __restrict__ b1,
    const u16* __restrict__ W2b, const float* __restrict__ b2,
    float* __restrict__ out) {
  __shared__ __align__(16) u16 F[128 * 168];
  __shared__ __align__(16) float winv[128];
  __shared__ __align__(16) float wnorm[128];
  __shared__ __align__(16) float outbuf[128 * 12];
  const int t = threadIdx.x;
  const int g = blockIdx.x;
  const int b = g >> 9;
  const int rbase = (g & 511) << 3;

  // ---- Phase A: build F = [p1 | p2[idx] | dir | 0-pad] --------------------
  {
    const int m = t >> 1, half = t & 1;
    const int n1 = rbase + (m >> 4);
    const uint4* s1p = (const uint4*)(p1t + ((size_t)(b * 4096 + n1) << 6)) + half * 4;
    uint4* d1p = (uint4*)(F + m * 168) + half * 4;
    d1p[0] = s1p[0]; d1p[1] = s1p[1]; d1p[2] = s1p[2]; d1p[3] = s1p[3];
    const int idx = knn[(((size_t)(b * 4096 + n1)) << 4) + (m & 15)];
    const uint4* s2p = (const uint4*)(p2t + ((size_t)(b * 4096 + idx) << 6)) + half * 4;
    uint4* d2p = (uint4*)(F + m * 168 + 64) + half * 4;
    d2p[0] = s2p[0]; d2p[1] = s2p[1]; d2p[2] = s2p[2]; d2p[3] = s2p[3];
  }
  if (t < 128) {
    const int m = t;
    const int n1 = rbase + (m >> 4);
    const int idx = knn[(((size_t)(b * 4096 + n1)) << 4) + (m & 15)];
    const float* X1 = xyz1 + b * 12288;
    const float* X2 = xyz2 + b * 12288;
    float dx = X2[idx] - X1[n1];
    float dy = X2[4096 + idx] - X1[4096 + n1];
    float dz = X2[8192 + idx] - X1[8192 + n1];
    u32 u0 = (u32)f2bf(dx) | ((u32)f2bf(dy) << 16);
    u32 u1 = (u32)f2bf(dz);
    uint4 pk = make_uint4(u0, u1, 0u, 0u);
    *(uint4*)(F + m * 168 + 128) = pk;
    float d = sqrtf(dx * dx + dy * dy + dz * dz);
    winv[m] = 1.0f / fmaxf(d, 1e-10f);
  } else {
    const int m = t - 128;
    uint4 zz = make_uint4(0u, 0u, 0u, 0u);
    uint4* zp = (uint4*)(F + m * 168 + 136);
    zp[0] = zz; zp[1] = zz; zp[2] = zz; zp[3] = zz;
  }
  __syncthreads();  // barrier 1: F + winv visible

  if (t < 128) {
    const int r = t >> 4;
    float s = 0.f;
#pragma unroll
    for (int k = 0; k < 16; k++) s += winv[(r << 4) + k];
    wnorm[t] = winv[t] / s;
  }

  const int lane = t & 63;
  const int wid = t >> 6;
  const int l15 = lane & 15;
  const int quad = lane >> 4;
  const int koff = quad << 3;
  const int nbase = wid << 5;

  // ---- GEMM1 -------------------------------------------------------------
  f32x4 acc[8][2];
  const f32x4 z4 = {0.f, 0.f, 0.f, 0.f};
#pragma unroll
  for (int i = 0; i < 8; i++)
#pragma unroll
    for (int j = 0; j < 2; j++) acc[i][j] = z4;

#pragma unroll
  for (int s = 0; s < 5; s++) {
    bf16x8 bf0 = ld16(W1b + (nbase + l15) * 160 + s * 32 + koff);
    bf16x8 bf1 = ld16(W1b + (nbase + 16 + l15) * 160 + s * 32 + koff);
#pragma unroll
    for (int mt = 0; mt < 8; mt++) {
      bf16x8 a = ld16(F + (mt * 16 + l15) * 168 + s * 32 + koff);
      acc[mt][0] = MFMA16(a, bf0, acc[mt][0]);
      acc[mt][1] = MFMA16(a, bf1, acc[mt][1]);
    }
  }
  __syncthreads();  // barrier 2: GEMM1 reads done before H1 overwrite

  {
    const float bv0 = b1[nbase + l15];
    const float bv1 = b1[nbase + 16 + l15];
#pragma unroll
    for (int mt = 0; mt < 8; mt++) {
      u16* hrow = F + (mt * 16 + quad * 4) * 168;
#pragma unroll
      for (int r = 0; r < 4; r++) {
        float zv0 = acc[mt][0][r] + bv0;
        zv0 = (zv0 >= 0.f) ? zv0 : 0.1f * zv0;
        hrow[r * 168 + nbase + l15] = f2bf(zv0);
        float zv1 = acc[mt][1][r] + bv1;
        zv1 = (zv1 >= 0.f) ? zv1 : 0.1f * zv1;
        hrow[r * 168 + nbase + 16 + l15] = f2bf(zv1);
      }
    }
  }
  __syncthreads();  // barrier 3: H1 visible

  // ---- GEMM2 -------------------------------------------------------------
  f32x4 acc2[8][2];
#pragma unroll
  for (int i = 0; i < 8; i++)
#pragma unroll
    for (int j = 0; j < 2; j++) acc2[i][j] = z4;

#pragma unroll
  for (int s = 0; s < 4; s++) {
    bf16x8 bf0 = ld16(W2b + (nbase + l15) * 128 + s * 32 + koff);
    bf16x8 bf1 = ld16(W2b + (nbase + 16 + l15) * 128 + s * 32 + koff);
#pragma unroll
    for (int mt = 0; mt < 8; mt++) {
      bf16x8 a = ld16(F + (mt * 16 + l15) * 168 + s * 32 + koff);
      acc2[mt][0] = MFMA16(a, bf0, acc2[mt][0]);
      acc2[mt][1] = MFMA16(a, bf1, acc2[mt][1]);
    }
  }

  {
    const float bv0 = b2[nbase + l15];
    const float bv1 = b2[nbase + 16 + l15];
#pragma unroll
    for (int mt = 0; mt < 8; mt++) {
      const f32x4 w4 = *(const f32x4*)&wnorm[(mt << 4) + (quad << 2)];
      float p0 = 0.f, p1 = 0.f;
#pragma unroll
      for (int r = 0; r < 4; r++) {
        float zv0 = acc2[mt][0][r] + bv0;
        zv0 = (zv0 >= 0.f) ? zv0 : 0.1f * zv0;
        p0 += zv0 * w4[r];
        float zv1 = acc2[mt][1][r] + bv1;
        zv1 = (zv1 >= 0.f) ? zv1 : 0.1f * zv1;
        p1 += zv1 * w4[r];
      }
      p0 += __shfl_xor(p0, 16); p0 += __shfl_xor(p0, 32);
      p1 += __shfl_xor(p1, 16); p1 += __shfl_xor(p1, 32);
      if (quad == 0) {
        outbuf[(nbase + l15) * 12 + mt] = p0;
        outbuf[(nbase + 16 + l15) * 12 + mt] = p1;
      }
    }
  }
  __syncthreads();  // barrier 4: outbuf visible
  {
    const int ch = t >> 1, half = t & 1;
    f32x4 v = *(const f32x4*)&outbuf[ch * 12 + (half << 2)];
    float* op = out + (((size_t)(b * 128 + ch)) << 12) + rbase + (half << 2);
    *(f32x4*)op = v;
  }
}

// ---------------------------------------------------------------------------
extern "C" void kernel_launch(void* const* d_in, const int* in_sizes, int n_in,
                              void* d_out, int out_size, void* d_ws, size_t ws_size,
                              hipStream_t stream) {
  const float* xyz1 = (const float*)d_in[0];
  const float* xyz2 = (const float*)d_in[1];
  const float* points1 = (const float*)d_in[2];
  const float* points2 = (const float*)d_in[3];
  const float* W1 = (const float*)d_in[4];
  const float* b1 = (const float*)d_in[5];
  const float* W2 = (const float*)d_in[6];
  const float* b2 = (const float*)d_in[7];
  float* out = (float*)d_out;

  char* ws = (char*)d_ws;
  int* knn = (int*)ws;                        // 1,048,576 B
  u16* p1t = (u16*)(ws + 1048576);            // 2,097,152 B
  u16* p2t = (u16*)(ws + 3145728);            // 2,097,152 B
  u16* W1b = (u16*)(ws + 5242880);            // 40,960 B
  u16* W2b = (u16*)(ws + 5283840);            // 32,768 B

  hipLaunchKernelGGL(knn_prep, dim3(512), dim3(512), 0, stream,
                     xyz1, xyz2, points1, points2, W1, W2, p1t, p2t, W1b, W2b, knn);
  hipLaunchKernelGGL(mlp_kernel, dim3(2048), dim3(256), 0, stream,
                     xyz1, xyz2, p1t, p2t, knn, W1b, b1, W2b, b2, out);
}